// Round 1
// baseline (1443.285 us; speedup 1.0000x reference)
//
#include <hip/hip_runtime.h>
#include <math.h>

// Problem constants (from reference)
#define HEADS 2
#define CH 64            // HID
#define FDIM 128         // HEADS*CH
#define INDIM 64
#define ODIM 32
#define NEG_SLOPE 0.2f

// ---------- order-preserving float<->uint encoding for atomicMax ----------
__device__ __forceinline__ unsigned enc_f32(float f) {
    unsigned u = __float_as_uint(f);
    return u ^ ((u & 0x80000000u) ? 0xFFFFFFFFu : 0x80000000u);
}
__device__ __forceinline__ float dec_f32(unsigned e) {
    unsigned u = (e & 0x80000000u) ? (e ^ 0x80000000u) : ~e;
    return __uint_as_float(u);
}

// ---------- init: out=bias (broadcast), amax=-inf(enc), denom=0 ----------
__global__ void k_init(float* __restrict__ gat_out, unsigned* __restrict__ amax,
                       float* __restrict__ denom, const float* __restrict__ bias, int n) {
    int i = blockIdx.x * blockDim.x + threadIdx.x;
    int total = n * FDIM;
    if (i < total) gat_out[i] = bias[i & (FDIM - 1)];
    if (i < n * HEADS) { amax[i] = 0x007FFFFFu; denom[i] = 0.f; }  // enc(-inf)
}

// ---------- xl = x@W [n,128]; a_src/a_dst [n,2] via wave reduction ----------
__global__ __launch_bounds__(256) void k_gemm_att(
    const float* __restrict__ x, const float* __restrict__ W,
    const float* __restrict__ att_src, const float* __restrict__ att_dst,
    float* __restrict__ xl, float* __restrict__ a_src, float* __restrict__ a_dst, int n)
{
    __shared__ float Ws[INDIM * FDIM];   // 32 KB
    __shared__ float xs[2][INDIM];
    int t = threadIdx.x;
    for (int i = t; i < INDIM * FDIM; i += 256) Ws[i] = W[i];
    int row0 = blockIdx.x * 2;
    if (t < 2 * INDIM) {
        int r = t >> 6, k = t & 63;
        xs[r][k] = (row0 + r < n) ? x[(size_t)(row0 + r) * INDIM + k] : 0.f;
    }
    __syncthreads();
    int rl  = t >> 7;            // local row (0/1)
    int col = t & (FDIM - 1);    // 0..127
    int row = row0 + rl;
    float acc = 0.f;
    #pragma unroll
    for (int k = 0; k < INDIM; ++k)
        acc = fmaf(xs[rl][k], Ws[k * FDIM + col], acc);
    if (row < n) xl[(size_t)row * FDIM + col] = acc;
    // attention dot products: each wave (64 lanes) == one (row, head)
    float ps = acc * att_src[col];
    float pd = acc * att_dst[col];
    #pragma unroll
    for (int off = 32; off > 0; off >>= 1) {
        ps += __shfl_down(ps, off, 64);
        pd += __shfl_down(pd, off, 64);
    }
    if ((t & 63) == 0 && row < n) {
        int h = (t >> 6) & 1;
        a_src[row * HEADS + h] = ps;
        a_dst[row * HEADS + h] = pd;
    }
}

// ---------- edge pass A: segment max via atomicMax ----------
__global__ void k_edge_max(const int* __restrict__ ei, int E_, int n,
                           const float* __restrict__ a_src, const float* __restrict__ a_dst,
                           unsigned* __restrict__ amax)
{
    int e = blockIdx.x * blockDim.x + threadIdx.x;
    if (e >= E_ + n) return;
    int s, d;
    if (e < E_) { s = ei[e]; d = ei[E_ + e]; } else { s = d = e - E_; }
    #pragma unroll
    for (int h = 0; h < HEADS; ++h) {
        float a = a_src[s * HEADS + h] + a_dst[d * HEADS + h];
        a = (a >= 0.f) ? a : NEG_SLOPE * a;
        atomicMax(&amax[d * HEADS + h], enc_f32(a));
    }
}

// ---------- edge pass B: ew = exp(alpha - amax[dst]); denom += ew ----------
__global__ void k_edge_exp(const int* __restrict__ ei, int E_, int n,
                           const float* __restrict__ a_src, const float* __restrict__ a_dst,
                           const unsigned* __restrict__ amax, float* __restrict__ denom,
                           float* __restrict__ ew)
{
    int e = blockIdx.x * blockDim.x + threadIdx.x;
    if (e >= E_ + n) return;
    int s, d;
    if (e < E_) { s = ei[e]; d = ei[E_ + e]; } else { s = d = e - E_; }
    #pragma unroll
    for (int h = 0; h < HEADS; ++h) {
        float a = a_src[s * HEADS + h] + a_dst[d * HEADS + h];
        a = (a >= 0.f) ? a : NEG_SLOPE * a;
        float v = expf(a - dec_f32(amax[d * HEADS + h]));
        ew[e * HEADS + h] = v;
        atomicAdd(&denom[d * HEADS + h], v);
    }
}

// ---------- normalize edge weights ----------
__global__ void k_norm(const int* __restrict__ ei, int E_, int n,
                       const float* __restrict__ denom, float* __restrict__ ew)
{
    int i = blockIdx.x * blockDim.x + threadIdx.x;
    if (i >= (E_ + n) * HEADS) return;
    int e = i >> 1, h = i & 1;
    int d = (e < E_) ? ei[E_ + e] : (e - E_);
    ew[i] = ew[i] / (denom[d * HEADS + h] + 1e-16f);
}

// ---------- scatter: out[dst] += xl[src] * ew  (128 threads per edge) ----------
__global__ __launch_bounds__(256) void k_scatter(
    const int* __restrict__ ei, int E_, int n,
    const float* __restrict__ xl, const float* __restrict__ ew,
    float* __restrict__ out)
{
    int t = threadIdx.x;
    int e = blockIdx.x * 2 + (t >> 7);
    int ch = t & (FDIM - 1);
    if (e >= E_ + n) return;
    int s, d;
    if (e < E_) { s = ei[e]; d = ei[E_ + e]; } else { s = d = e - E_; }
    float w = ew[e * HEADS + (ch >> 6)];
    float v = xl[(size_t)s * FDIM + ch] * w;
    atomicAdd(&out[(size_t)d * FDIM + ch], v);
}

// ---------- h = elu(gat_out) @ fcw + fcb  [n,128]@[128,64] ----------
__global__ __launch_bounds__(256) void k_elu_fc(
    const float* __restrict__ in, const float* __restrict__ fcw,
    const float* __restrict__ fcb, float* __restrict__ out, int n)
{
    __shared__ float Ws[FDIM * CH];   // 32 KB
    __shared__ float xs[4][FDIM];
    int t = threadIdx.x;
    for (int i = t; i < FDIM * CH; i += 256) Ws[i] = fcw[i];
    int row0 = blockIdx.x * 4;
    for (int i = t; i < 4 * FDIM; i += 256) {
        int r = i >> 7, k = i & 127;
        float v = (row0 + r < n) ? in[(size_t)(row0 + r) * FDIM + k] : 0.f;
        xs[r][k] = (v > 0.f) ? v : expm1f(v);   // jax.nn.elu
    }
    __syncthreads();
    int rl = t >> 6, col = t & 63;
    int row = row0 + rl;
    float acc = fcb[col];
    #pragma unroll
    for (int k = 0; k < FDIM; ++k) acc = fmaf(xs[rl][k], Ws[k * CH + col], acc);
    if (row < n) out[(size_t)row * CH + col] = acc;
}

// ---------- logits + gumbel + softmax(32) ----------
__global__ __launch_bounds__(256) void k_final(
    const float* __restrict__ h, const float* __restrict__ out_w,
    const float* __restrict__ out_b, const float* __restrict__ gu,
    float* __restrict__ out, int n)
{
    __shared__ float Ws[CH * ODIM];   // 8 KB
    __shared__ float xs[8][CH];
    int t = threadIdx.x;
    for (int i = t; i < CH * ODIM; i += 256) Ws[i] = out_w[i];
    int row0 = blockIdx.x * 8;
    for (int i = t; i < 8 * CH; i += 256) {
        int r = i >> 6, k = i & 63;
        xs[r][k] = (row0 + r < n) ? h[(size_t)(row0 + r) * CH + k] : 0.f;
    }
    __syncthreads();
    int rl = t >> 5, col = t & 31;
    int row = row0 + rl;
    float acc = out_b[col];
    #pragma unroll
    for (int k = 0; k < CH; ++k) acc = fmaf(xs[rl][k], Ws[k * ODIM + col], acc);
    float u = (row < n) ? gu[(size_t)row * ODIM + col] : 0.5f;
    float g = -logf(-logf(u + 1e-20f) + 1e-20f);
    float z = acc + g;                 // TEMP = 1
    float m = z;
    #pragma unroll
    for (int off = 16; off > 0; off >>= 1) m = fmaxf(m, __shfl_xor(m, off, 32));
    float ex = expf(z - m);
    float sum = ex;
    #pragma unroll
    for (int off = 16; off > 0; off >>= 1) sum += __shfl_xor(sum, off, 32);
    if (row < n) out[(size_t)row * ODIM + col] = ex / sum;
}

extern "C" void kernel_launch(void* const* d_in, const int* in_sizes, int n_in,
                              void* d_out, int out_size, void* d_ws, size_t ws_size,
                              hipStream_t stream) {
    const float* x        = (const float*)d_in[0];
    const int*   ei       = (const int*)  d_in[1];
    const float* W0       = (const float*)d_in[2];
    const float* att_src0 = (const float*)d_in[3];
    const float* att_dst0 = (const float*)d_in[4];
    const float* bias0    = (const float*)d_in[5];
    const float* fcw0     = (const float*)d_in[6];
    const float* fcb0     = (const float*)d_in[7];
    const float* W1       = (const float*)d_in[8];
    const float* att_src1 = (const float*)d_in[9];
    const float* att_dst1 = (const float*)d_in[10];
    const float* bias1    = (const float*)d_in[11];
    const float* fcw1     = (const float*)d_in[12];
    const float* fcb1     = (const float*)d_in[13];
    const float* out_w    = (const float*)d_in[14];
    const float* out_b    = (const float*)d_in[15];
    const float* gu       = (const float*)d_in[16];

    const int N_ = in_sizes[0] / INDIM;
    const int E_ = in_sizes[1] / 2;
    const int TE = E_ + N_;            // edges incl. self-loops

    float* ws = (float*)d_ws;
    size_t off = 0;
    float*    xl    = ws + off; off += (size_t)N_ * FDIM;
    float*    gat   = ws + off; off += (size_t)N_ * FDIM;
    float*    h1    = ws + off; off += (size_t)N_ * CH;
    float*    h2    = ws + off; off += (size_t)N_ * CH;
    float*    a_src = ws + off; off += (size_t)N_ * HEADS;
    float*    a_dst = ws + off; off += (size_t)N_ * HEADS;
    unsigned* amax  = (unsigned*)(ws + off); off += (size_t)N_ * HEADS;
    float*    denom = ws + off; off += (size_t)N_ * HEADS;
    float*    ew    = ws + off; off += (size_t)TE * HEADS;

    const int B = 256;
    dim3 blk(B);
    int g_init  = (N_ * FDIM + B - 1) / B;
    int g_gemm  = (N_ + 1) / 2;
    int g_edge  = (TE + B - 1) / B;
    int g_norm  = (TE * HEADS + B - 1) / B;
    int g_scat  = (TE + 1) / 2;
    int g_fc    = (N_ + 3) / 4;
    int g_fin   = (N_ + 7) / 8;

    // ---- layer 1 ----
    k_init     <<<g_init, blk, 0, stream>>>(gat, amax, denom, bias0, N_);
    k_gemm_att <<<g_gemm, blk, 0, stream>>>(x, W0, att_src0, att_dst0, xl, a_src, a_dst, N_);
    k_edge_max <<<g_edge, blk, 0, stream>>>(ei, E_, N_, a_src, a_dst, amax);
    k_edge_exp <<<g_edge, blk, 0, stream>>>(ei, E_, N_, a_src, a_dst, amax, denom, ew);
    k_norm     <<<g_norm, blk, 0, stream>>>(ei, E_, N_, denom, ew);
    k_scatter  <<<g_scat, blk, 0, stream>>>(ei, E_, N_, xl, ew, gat);
    k_elu_fc   <<<g_fc,   blk, 0, stream>>>(gat, fcw0, fcb0, h1, N_);

    // ---- layer 2 ----
    k_init     <<<g_init, blk, 0, stream>>>(gat, amax, denom, bias1, N_);
    k_gemm_att <<<g_gemm, blk, 0, stream>>>(h1, W1, att_src1, att_dst1, xl, a_src, a_dst, N_);
    k_edge_max <<<g_edge, blk, 0, stream>>>(ei, E_, N_, a_src, a_dst, amax);
    k_edge_exp <<<g_edge, blk, 0, stream>>>(ei, E_, N_, a_src, a_dst, amax, denom, ew);
    k_norm     <<<g_norm, blk, 0, stream>>>(ei, E_, N_, denom, ew);
    k_scatter  <<<g_scat, blk, 0, stream>>>(ei, E_, N_, xl, ew, gat);
    k_elu_fc   <<<g_fc,   blk, 0, stream>>>(gat, fcw1, fcb1, h2, N_);

    // ---- head ----
    k_final    <<<g_fin,  blk, 0, stream>>>(h2, out_w, out_b, gu, (float*)d_out, N_);
}

// Round 2
// 665.530 us; speedup vs baseline: 2.1686x; 2.1686x over previous
//
#include <hip/hip_runtime.h>
#include <math.h>

#define HEADS 2
#define CH 64            // HID
#define FDIM 128         // HEADS*CH
#define INDIM 64
#define ODIM 32
#define NEG_SLOPE 0.2f
#define SCAN_B 256

// ---------------- CSR build ----------------
__global__ void k_zero(int* __restrict__ p, int n) {
    int i = blockIdx.x * blockDim.x + threadIdx.x;
    if (i < n) p[i] = 0;
}

__global__ void k_count(const int* __restrict__ ei, int E_, int* __restrict__ deg) {
    int e = blockIdx.x * blockDim.x + threadIdx.x;
    if (e < E_) atomicAdd(&deg[ei[E_ + e]], 1);
}

// block-level exclusive scan (Hillis-Steele in LDS)
__global__ void k_scan1(const int* __restrict__ deg, int* __restrict__ offs,
                        int* __restrict__ bsum, int n) {
    __shared__ int sh[SCAN_B];
    int t = threadIdx.x;
    int i = blockIdx.x * SCAN_B + t;
    int v = (i < n) ? deg[i] : 0;
    sh[t] = v;
    __syncthreads();
    for (int off = 1; off < SCAN_B; off <<= 1) {
        int add = (t >= off) ? sh[t - off] : 0;
        __syncthreads();
        sh[t] += add;
        __syncthreads();
    }
    if (i < n) offs[i] = sh[t] - v;          // exclusive
    if (t == SCAN_B - 1) bsum[blockIdx.x] = sh[t];
}

__global__ void k_scan2(int* __restrict__ bsum, int nb) {
    __shared__ int sh[1024];
    int t = threadIdx.x;
    int v = (t < nb) ? bsum[t] : 0;
    sh[t] = v;
    __syncthreads();
    for (int off = 1; off < 1024; off <<= 1) {
        int add = (t >= off) ? sh[t - off] : 0;
        __syncthreads();
        sh[t] += add;
        __syncthreads();
    }
    if (t < nb) bsum[t] = sh[t] - v;         // exclusive block offsets
}

__global__ void k_scan3(int* __restrict__ offs, const int* __restrict__ bsum,
                        int* __restrict__ pos, int n) {
    int i = blockIdx.x * blockDim.x + threadIdx.x;
    if (i < n) {
        int v = offs[i] + bsum[i >> 8];      // blockDim==256
        offs[i] = v;
        pos[i] = v;
    }
}

__global__ void k_fill(const int* __restrict__ ei, int E_, int* __restrict__ pos,
                       int* __restrict__ csr_src) {
    int e = blockIdx.x * blockDim.x + threadIdx.x;
    if (e < E_) {
        int d = ei[E_ + e];
        int slot = atomicAdd(&pos[d], 1);
        csr_src[slot] = ei[e];
    }
}

// ---------- xl = x@W [n,128]; a_src/a_dst [n,2]; 8 rows per block ----------
__global__ __launch_bounds__(256) void k_gemm_att(
    const float* __restrict__ x, const float* __restrict__ W,
    const float* __restrict__ att_src, const float* __restrict__ att_dst,
    float* __restrict__ xl, float* __restrict__ a_src, float* __restrict__ a_dst, int n)
{
    __shared__ float Ws[INDIM * FDIM];   // 32 KB
    __shared__ float xs[8][INDIM];       // 2 KB
    int t = threadIdx.x;
    for (int i = t; i < INDIM * FDIM; i += 256) Ws[i] = W[i];
    int row0 = blockIdx.x * 8;
    for (int i = t; i < 8 * INDIM; i += 256) {
        int r = i >> 6, k = i & 63;
        xs[r][k] = (row0 + r < n) ? x[(size_t)(row0 + r) * INDIM + k] : 0.f;
    }
    __syncthreads();
    int col = t & (FDIM - 1);
    int rbase = t >> 7;
    int h = col >> 6;
    float as_c = att_src[col], ad_c = att_dst[col];
    #pragma unroll
    for (int i = 0; i < 4; ++i) {
        int r = rbase + 2 * i;
        int row = row0 + r;
        float acc = 0.f;
        #pragma unroll
        for (int k = 0; k < INDIM; ++k)
            acc = fmaf(xs[r][k], Ws[k * FDIM + col], acc);
        if (row < n) xl[(size_t)row * FDIM + col] = acc;
        float ps = acc * as_c, pd = acc * ad_c;
        #pragma unroll
        for (int off = 32; off > 0; off >>= 1) {
            ps += __shfl_down(ps, off, 64);
            pd += __shfl_down(pd, off, 64);
        }
        if ((t & 63) == 0 && row < n) {
            a_src[row * HEADS + h] = ps;
            a_dst[row * HEADS + h] = pd;
        }
    }
}

// ---------- fused edge pipeline: per-dst gather, softmax-free-of-max ----------
// out[d] = (sum_e w_e * xl[src_e]) / (sum_e w_e + 1e-16) + bias,
// w_e = exp(leakyrelu(a_src[s]+a_dst[d]))   (max-shift dropped: identity)
__global__ __launch_bounds__(256) void k_gather(
    const int* __restrict__ offs, const int* __restrict__ csr_src, int E_,
    const float* __restrict__ xl, const float* __restrict__ a_src,
    const float* __restrict__ a_dst, const float* __restrict__ bias,
    float* __restrict__ out, int n)
{
    int t = threadIdx.x;
    int d = blockIdx.x * 2 + (t >> 7);
    if (d >= n) return;
    int ch = t & (FDIM - 1);
    int h = ch >> 6;
    int start = offs[d];
    int end = (d + 1 < n) ? offs[d + 1] : E_;
    float ad = a_dst[d * HEADS + h];
    float acc = 0.f, den = 0.f;
    int s_next = (start < end) ? csr_src[start] : 0;
    for (int j = start; j < end; ++j) {
        int s = s_next;
        if (j + 1 < end) s_next = csr_src[j + 1];
        float a = a_src[s * HEADS + h] + ad;
        a = (a >= 0.f) ? a : NEG_SLOPE * a;
        float w = expf(a);
        acc = fmaf(w, xl[(size_t)s * FDIM + ch], acc);
        den += w;
    }
    // self-loop (src = dst = d)
    {
        float a = a_src[d * HEADS + h] + ad;
        a = (a >= 0.f) ? a : NEG_SLOPE * a;
        float w = expf(a);
        acc = fmaf(w, xl[(size_t)d * FDIM + ch], acc);
        den += w;
    }
    out[(size_t)d * FDIM + ch] = acc / (den + 1e-16f) + bias[ch];
}

// ---------- h = elu(gat_out) @ fcw + fcb  [n,128]@[128,64] ----------
__global__ __launch_bounds__(256) void k_elu_fc(
    const float* __restrict__ in, const float* __restrict__ fcw,
    const float* __restrict__ fcb, float* __restrict__ out, int n)
{
    __shared__ float Ws[FDIM * CH];   // 32 KB
    __shared__ float xs[4][FDIM];
    int t = threadIdx.x;
    for (int i = t; i < FDIM * CH; i += 256) Ws[i] = fcw[i];
    int row0 = blockIdx.x * 4;
    for (int i = t; i < 4 * FDIM; i += 256) {
        int r = i >> 7, k = i & 127;
        float v = (row0 + r < n) ? in[(size_t)(row0 + r) * FDIM + k] : 0.f;
        xs[r][k] = (v > 0.f) ? v : expm1f(v);   // jax.nn.elu
    }
    __syncthreads();
    int rl = t >> 6, col = t & 63;
    int row = row0 + rl;
    float acc = fcb[col];
    #pragma unroll
    for (int k = 0; k < FDIM; ++k) acc = fmaf(xs[rl][k], Ws[k * CH + col], acc);
    if (row < n) out[(size_t)row * CH + col] = acc;
}

// ---------- logits + gumbel + softmax(32) ----------
__global__ __launch_bounds__(256) void k_final(
    const float* __restrict__ h, const float* __restrict__ out_w,
    const float* __restrict__ out_b, const float* __restrict__ gu,
    float* __restrict__ out, int n)
{
    __shared__ float Ws[CH * ODIM];   // 8 KB
    __shared__ float xs[8][CH];
    int t = threadIdx.x;
    for (int i = t; i < CH * ODIM; i += 256) Ws[i] = out_w[i];
    int row0 = blockIdx.x * 8;
    for (int i = t; i < 8 * CH; i += 256) {
        int r = i >> 6, k = i & 63;
        xs[r][k] = (row0 + r < n) ? h[(size_t)(row0 + r) * CH + k] : 0.f;
    }
    __syncthreads();
    int rl = t >> 5, col = t & 31;
    int row = row0 + rl;
    float acc = out_b[col];
    #pragma unroll
    for (int k = 0; k < CH; ++k) acc = fmaf(xs[rl][k], Ws[k * ODIM + col], acc);
    float u = (row < n) ? gu[(size_t)row * ODIM + col] : 0.5f;
    float g = -logf(-logf(u + 1e-20f) + 1e-20f);
    float z = acc + g;                 // TEMP = 1
    float m = z;
    #pragma unroll
    for (int off = 16; off > 0; off >>= 1) m = fmaxf(m, __shfl_xor(m, off, 32));
    float ex = expf(z - m);
    float sum = ex;
    #pragma unroll
    for (int off = 16; off > 0; off >>= 1) sum += __shfl_xor(sum, off, 32);
    if (row < n) out[(size_t)row * ODIM + col] = ex / sum;
}

extern "C" void kernel_launch(void* const* d_in, const int* in_sizes, int n_in,
                              void* d_out, int out_size, void* d_ws, size_t ws_size,
                              hipStream_t stream) {
    const float* x        = (const float*)d_in[0];
    const int*   ei       = (const int*)  d_in[1];
    const float* W0       = (const float*)d_in[2];
    const float* att_src0 = (const float*)d_in[3];
    const float* att_dst0 = (const float*)d_in[4];
    const float* bias0    = (const float*)d_in[5];
    const float* fcw0     = (const float*)d_in[6];
    const float* fcb0     = (const float*)d_in[7];
    const float* W1       = (const float*)d_in[8];
    const float* att_src1 = (const float*)d_in[9];
    const float* att_dst1 = (const float*)d_in[10];
    const float* bias1    = (const float*)d_in[11];
    const float* fcw1     = (const float*)d_in[12];
    const float* fcb1     = (const float*)d_in[13];
    const float* out_w    = (const float*)d_in[14];
    const float* out_b    = (const float*)d_in[15];
    const float* gu       = (const float*)d_in[16];

    const int N_ = in_sizes[0] / INDIM;
    const int E_ = in_sizes[1] / 2;

    float* ws = (float*)d_ws;
    size_t off = 0;
    float* xl    = ws + off; off += (size_t)N_ * FDIM;
    float* gat   = ws + off; off += (size_t)N_ * FDIM;
    float* h1    = ws + off; off += (size_t)N_ * CH;
    float* h2    = ws + off; off += (size_t)N_ * CH;
    float* a_src = ws + off; off += (size_t)N_ * HEADS;
    float* a_dst = ws + off; off += (size_t)N_ * HEADS;
    int* deg     = (int*)(ws + off); off += N_;
    int* offs    = (int*)(ws + off); off += N_;
    int* pos     = (int*)(ws + off); off += N_;
    int* bsum    = (int*)(ws + off); off += 1024;
    int* csr_src = (int*)(ws + off); off += E_;

    const int B = 256;
    dim3 blk(B);
    int nb      = (N_ + SCAN_B - 1) / SCAN_B;
    int g_n     = (N_ + B - 1) / B;
    int g_e     = (E_ + B - 1) / B;
    int g_gemm  = (N_ + 7) / 8;
    int g_gath  = (N_ + 1) / 2;
    int g_fc    = (N_ + 3) / 4;
    int g_fin   = (N_ + 7) / 8;

    // ---- CSR build (shared by both layers) ----
    k_zero  <<<g_n, blk, 0, stream>>>(deg, N_);
    k_count <<<g_e, blk, 0, stream>>>(ei, E_, deg);
    k_scan1 <<<nb, dim3(SCAN_B), 0, stream>>>(deg, offs, bsum, N_);
    k_scan2 <<<1, dim3(1024), 0, stream>>>(bsum, nb);
    k_scan3 <<<g_n, blk, 0, stream>>>(offs, bsum, pos, N_);
    k_fill  <<<g_e, blk, 0, stream>>>(ei, E_, pos, csr_src);

    // ---- layer 1 ----
    k_gemm_att <<<g_gemm, blk, 0, stream>>>(x, W0, att_src0, att_dst0, xl, a_src, a_dst, N_);
    k_gather   <<<g_gath, blk, 0, stream>>>(offs, csr_src, E_, xl, a_src, a_dst, bias0, gat, N_);
    k_elu_fc   <<<g_fc,   blk, 0, stream>>>(gat, fcw0, fcb0, h1, N_);

    // ---- layer 2 ----
    k_gemm_att <<<g_gemm, blk, 0, stream>>>(h1, W1, att_src1, att_dst1, xl, a_src, a_dst, N_);
    k_gather   <<<g_gath, blk, 0, stream>>>(offs, csr_src, E_, xl, a_src, a_dst, bias1, gat, N_);
    k_elu_fc   <<<g_fc,   blk, 0, stream>>>(gat, fcw1, fcb1, h2, N_);

    // ---- head ----
    k_final    <<<g_fin, blk, 0, stream>>>(h2, out_w, out_b, gu, (float*)d_out, N_);
}

// Round 3
// 461.360 us; speedup vs baseline: 3.1283x; 1.4425x over previous
//
#include <hip/hip_runtime.h>
#include <hip/hip_fp16.h>
#include <math.h>

#define HEADS 2
#define FDIM 128
#define INDIM 64
#define ODIM 32
#define NEG_SLOPE 0.2f
#define SCAN_B 256

__device__ __forceinline__ float elu1(float v) { return v > 0.f ? v : expm1f(v); }

// ---------------- CSR build ----------------
__global__ void k_zero(int* __restrict__ p, int n) {
    int i = blockIdx.x * blockDim.x + threadIdx.x;
    if (i < n) p[i] = 0;
}

__global__ void k_count(const int* __restrict__ ei, int E_, int* __restrict__ deg) {
    int e = blockIdx.x * blockDim.x + threadIdx.x;
    if (e < E_) atomicAdd(&deg[ei[E_ + e]], 1);
}

__global__ void k_scan1(const int* __restrict__ deg, int* __restrict__ offs,
                        int* __restrict__ bsum, int n) {
    __shared__ int sh[SCAN_B];
    int t = threadIdx.x;
    int i = blockIdx.x * SCAN_B + t;
    int v = (i < n) ? deg[i] : 0;
    sh[t] = v;
    __syncthreads();
    for (int off = 1; off < SCAN_B; off <<= 1) {
        int add = (t >= off) ? sh[t - off] : 0;
        __syncthreads();
        sh[t] += add;
        __syncthreads();
    }
    if (i < n) offs[i] = sh[t] - v;
    if (t == SCAN_B - 1) bsum[blockIdx.x] = sh[t];
}

__global__ void k_scan2(int* __restrict__ bsum, int nb) {
    __shared__ int sh[1024];
    int t = threadIdx.x;
    int v = (t < nb) ? bsum[t] : 0;
    sh[t] = v;
    __syncthreads();
    for (int off = 1; off < 1024; off <<= 1) {
        int add = (t >= off) ? sh[t - off] : 0;
        __syncthreads();
        sh[t] += add;
        __syncthreads();
    }
    if (t < nb) bsum[t] = sh[t] - v;
}

__global__ void k_scan3(int* __restrict__ offs, const int* __restrict__ bsum,
                        int* __restrict__ pos, int n) {
    int i = blockIdx.x * blockDim.x + threadIdx.x;
    if (i < n) {
        int v = offs[i] + bsum[i >> 8];
        offs[i] = v;
        pos[i] = v;
    }
}

__global__ void k_fill(const int* __restrict__ ei, int E_, int* __restrict__ pos,
                       int* __restrict__ csr_src) {
    int e = blockIdx.x * blockDim.x + threadIdx.x;
    if (e < E_) {
        int d = ei[E_ + e];
        int slot = atomicAdd(&pos[d], 1);
        csr_src[slot] = ei[e];
    }
}

// ---------- fused weight precompute: Wf = fcw0@W1, bf = fcb0@W1 ----------
//                                    Wfo = fcw1@out_w, bfo = fcb1@out_w + out_b
__global__ __launch_bounds__(128) void k_fuse_w(
    const float* __restrict__ fcw0, const float* __restrict__ fcb0, const float* __restrict__ W1,
    const float* __restrict__ fcw1, const float* __restrict__ fcb1,
    const float* __restrict__ out_w, const float* __restrict__ out_b,
    float* __restrict__ Wf, float* __restrict__ bf,
    float* __restrict__ Wfo, float* __restrict__ bfo)
{
    int b = blockIdx.x, c = threadIdx.x;
    if (b < 129) {
        float acc = 0.f;
        if (b < 128) {
            for (int j = 0; j < 64; ++j) acc = fmaf(fcw0[b * 64 + j], W1[j * 128 + c], acc);
            Wf[b * 128 + c] = acc;
        } else {
            for (int j = 0; j < 64; ++j) acc = fmaf(fcb0[j], W1[j * 128 + c], acc);
            bf[c] = acc;
        }
    } else {
        int k = b - 129;
        if (c < 32) {
            float acc = 0.f;
            if (k < 128) {
                for (int j = 0; j < 64; ++j) acc = fmaf(fcw1[k * 64 + j], out_w[j * 32 + c], acc);
                Wfo[k * 32 + c] = acc;
            } else {
                for (int j = 0; j < 64; ++j) acc = fmaf(fcb1[j], out_w[j * 32 + c], acc);
                bfo[c] = acc + out_b[c];
            }
        }
    }
}

// ---------- layer-1 GEMM+att: W in VGPRs, x staged in LDS, b128 broadcast ----------
__global__ __launch_bounds__(256, 4) void k_gemm_att1(
    const float* __restrict__ x, const float* __restrict__ W,
    const float* __restrict__ att_src, const float* __restrict__ att_dst,
    __half* __restrict__ xl, float* __restrict__ a_src, float* __restrict__ a_dst, int n)
{
    __shared__ float4 xs4[64 * 16];   // 64 rows x 64 k  (16 KB)
    int t = threadIdx.x;
    int row0 = blockIdx.x * 64;
    for (int i = t; i < 64 * 16; i += 256) {
        int row = row0 + (i >> 4);
        xs4[i] = (row < n) ? ((const float4*)x)[(size_t)row * 16 + (i & 15)]
                           : make_float4(0.f, 0.f, 0.f, 0.f);
    }
    int col = t & 127;
    int half_ = t >> 7;
    float wr[64];
    #pragma unroll
    for (int k = 0; k < 64; ++k) wr[k] = W[k * 128 + col];
    float as_c = att_src[col], ad_c = att_dst[col];
    int h = col >> 6;
    __syncthreads();
    for (int rl = half_ * 32; rl < half_ * 32 + 32; ++rl) {
        int row = row0 + rl;
        float a0 = 0.f, a1 = 0.f, a2 = 0.f, a3 = 0.f;
        #pragma unroll
        for (int kq = 0; kq < 16; ++kq) {
            float4 xv = xs4[rl * 16 + kq];
            a0 = fmaf(xv.x, wr[kq * 4 + 0], a0);
            a1 = fmaf(xv.y, wr[kq * 4 + 1], a1);
            a2 = fmaf(xv.z, wr[kq * 4 + 2], a2);
            a3 = fmaf(xv.w, wr[kq * 4 + 3], a3);
        }
        float v = (a0 + a1) + (a2 + a3);
        if (row < n) xl[(size_t)row * 128 + col] = __float2half(v);
        float ps = v * as_c, pd = v * ad_c;
        #pragma unroll
        for (int off = 32; off > 0; off >>= 1) {
            ps += __shfl_down(ps, off, 64);
            pd += __shfl_down(pd, off, 64);
        }
        if ((t & 63) == 0 && row < n) {
            a_src[row * 2 + h] = ps;
            a_dst[row * 2 + h] = pd;
        }
    }
}

// ---------- layer-2 GEMM+att: elu(gat)@Wf + bf, fused fc+gemm ----------
__global__ __launch_bounds__(256, 2) void k_gemm_att2(
    const float* __restrict__ g, const float* __restrict__ Wf, const float* __restrict__ bf,
    const float* __restrict__ att_src, const float* __restrict__ att_dst,
    __half* __restrict__ xl, float* __restrict__ a_src, float* __restrict__ a_dst, int n)
{
    __shared__ float4 xs4[64 * 32];   // 64 rows x 128 k  (32 KB)
    int t = threadIdx.x;
    int row0 = blockIdx.x * 64;
    for (int i = t; i < 64 * 32; i += 256) {
        int row = row0 + (i >> 5);
        float4 v = (row < n) ? ((const float4*)g)[(size_t)row * 32 + (i & 31)]
                             : make_float4(0.f, 0.f, 0.f, 0.f);
        v.x = elu1(v.x); v.y = elu1(v.y); v.z = elu1(v.z); v.w = elu1(v.w);
        xs4[i] = v;
    }
    int col = t & 127;
    int half_ = t >> 7;
    float wr[128];
    #pragma unroll
    for (int k = 0; k < 128; ++k) wr[k] = Wf[k * 128 + col];
    float bc = bf[col];
    float as_c = att_src[col], ad_c = att_dst[col];
    int h = col >> 6;
    __syncthreads();
    for (int rl = half_ * 32; rl < half_ * 32 + 32; ++rl) {
        int row = row0 + rl;
        float a0 = 0.f, a1 = 0.f, a2 = 0.f, a3 = 0.f;
        #pragma unroll
        for (int kq = 0; kq < 32; ++kq) {
            float4 xv = xs4[rl * 32 + kq];
            a0 = fmaf(xv.x, wr[kq * 4 + 0], a0);
            a1 = fmaf(xv.y, wr[kq * 4 + 1], a1);
            a2 = fmaf(xv.z, wr[kq * 4 + 2], a2);
            a3 = fmaf(xv.w, wr[kq * 4 + 3], a3);
        }
        float v = (a0 + a1) + (a2 + a3) + bc;
        if (row < n) xl[(size_t)row * 128 + col] = __float2half(v);
        float ps = v * as_c, pd = v * ad_c;
        #pragma unroll
        for (int off = 32; off > 0; off >>= 1) {
            ps += __shfl_down(ps, off, 64);
            pd += __shfl_down(pd, off, 64);
        }
        if ((t & 63) == 0 && row < n) {
            a_src[row * 2 + h] = ps;
            a_dst[row * 2 + h] = pd;
        }
    }
}

// ---------- gather v3: 1 wave/dst, 4 edges/iter, fp16 xl as dwordx4 ----------
__global__ __launch_bounds__(256, 4) void k_gather(
    const int* __restrict__ offs, const int* __restrict__ csr_src, int E_,
    const __half* __restrict__ xl, const float* __restrict__ a_src,
    const float* __restrict__ a_dst, const float* __restrict__ bias,
    float* __restrict__ out, int n)
{
    int t = threadIdx.x;
    int lane = t & 63;
    int d = blockIdx.x * 4 + (t >> 6);
    if (d >= n) return;
    int eh = lane >> 4;          // edge slot 0..3
    int cq = lane & 15;          // channels cq*8 .. cq*8+7
    int h = cq >> 3;
    float ad = a_dst[d * 2 + h];
    const float4* bp = (const float4*)(bias + cq * 8);
    float4 b0 = bp[0], b1 = bp[1];
    int start = offs[d];
    int end = (d + 1 < n) ? offs[d + 1] : E_;
    float acc[8] = {0.f, 0.f, 0.f, 0.f, 0.f, 0.f, 0.f, 0.f};
    float den = 0.f;
    for (int j0 = start; j0 < end; j0 += 4) {
        int j = j0 + eh;
        bool valid = j < end;
        int s = valid ? csr_src[j] : d;
        float a = a_src[s * 2 + h] + ad;
        a = (a >= 0.f) ? a : NEG_SLOPE * a;
        float w = valid ? __expf(a) : 0.f;
        float4 raw = *(const float4*)(xl + (size_t)s * 128 + cq * 8);
        __half2* hp = (__half2*)&raw;
        float2 f0 = __half22float2(hp[0]);
        float2 f1 = __half22float2(hp[1]);
        float2 f2 = __half22float2(hp[2]);
        float2 f3 = __half22float2(hp[3]);
        acc[0] = fmaf(w, f0.x, acc[0]); acc[1] = fmaf(w, f0.y, acc[1]);
        acc[2] = fmaf(w, f1.x, acc[2]); acc[3] = fmaf(w, f1.y, acc[3]);
        acc[4] = fmaf(w, f2.x, acc[4]); acc[5] = fmaf(w, f2.y, acc[5]);
        acc[6] = fmaf(w, f3.x, acc[6]); acc[7] = fmaf(w, f3.y, acc[7]);
        den += w;
    }
    if (eh == 0) {   // self-loop, counted once
        float a = a_src[d * 2 + h] + ad;
        a = (a >= 0.f) ? a : NEG_SLOPE * a;
        float w = __expf(a);
        float4 raw = *(const float4*)(xl + (size_t)d * 128 + cq * 8);
        __half2* hp = (__half2*)&raw;
        float2 f0 = __half22float2(hp[0]);
        float2 f1 = __half22float2(hp[1]);
        float2 f2 = __half22float2(hp[2]);
        float2 f3 = __half22float2(hp[3]);
        acc[0] = fmaf(w, f0.x, acc[0]); acc[1] = fmaf(w, f0.y, acc[1]);
        acc[2] = fmaf(w, f1.x, acc[2]); acc[3] = fmaf(w, f1.y, acc[3]);
        acc[4] = fmaf(w, f2.x, acc[4]); acc[5] = fmaf(w, f2.y, acc[5]);
        acc[6] = fmaf(w, f3.x, acc[6]); acc[7] = fmaf(w, f3.y, acc[7]);
        den += w;
    }
    #pragma unroll
    for (int i = 0; i < 8; ++i) {
        acc[i] += __shfl_xor(acc[i], 16, 64);
        acc[i] += __shfl_xor(acc[i], 32, 64);
    }
    den += __shfl_xor(den, 16, 64);
    den += __shfl_xor(den, 32, 64);
    if (eh == 0) {
        float inv = 1.f / (den + 1e-16f);
        float4 o0 = make_float4(fmaf(acc[0], inv, b0.x), fmaf(acc[1], inv, b0.y),
                                fmaf(acc[2], inv, b0.z), fmaf(acc[3], inv, b0.w));
        float4 o1 = make_float4(fmaf(acc[4], inv, b1.x), fmaf(acc[5], inv, b1.y),
                                fmaf(acc[6], inv, b1.z), fmaf(acc[7], inv, b1.w));
        float4* op = (float4*)(out + (size_t)d * 128 + cq * 8);
        op[0] = o0; op[1] = o1;
    }
}

// ---------- final: elu(gat2)@Wfo + bfo + gumbel + softmax(32) ----------
__global__ __launch_bounds__(256, 2) void k_final(
    const float* __restrict__ g, const float* __restrict__ Wfo, const float* __restrict__ bfo,
    const float* __restrict__ gu, float* __restrict__ out, int n)
{
    __shared__ float4 xs4[64 * 32];   // 32 KB
    int t = threadIdx.x;
    int row0 = blockIdx.x * 64;
    for (int i = t; i < 64 * 32; i += 256) {
        int row = row0 + (i >> 5);
        float4 v = (row < n) ? ((const float4*)g)[(size_t)row * 32 + (i & 31)]
                             : make_float4(0.f, 0.f, 0.f, 0.f);
        v.x = elu1(v.x); v.y = elu1(v.y); v.z = elu1(v.z); v.w = elu1(v.w);
        xs4[i] = v;
    }
    int col = t & 31;
    int rg = t >> 5;   // 0..7
    float wr[128];
    #pragma unroll
    for (int k = 0; k < 128; ++k) wr[k] = Wfo[k * 32 + col];
    float bc = bfo[col];
    __syncthreads();
    for (int rr = 0; rr < 8; ++rr) {
        int rl = rg * 8 + rr;
        int row = row0 + rl;
        float a0 = 0.f, a1 = 0.f, a2 = 0.f, a3 = 0.f;
        #pragma unroll
        for (int kq = 0; kq < 32; ++kq) {
            float4 xv = xs4[rl * 32 + kq];
            a0 = fmaf(xv.x, wr[kq * 4 + 0], a0);
            a1 = fmaf(xv.y, wr[kq * 4 + 1], a1);
            a2 = fmaf(xv.z, wr[kq * 4 + 2], a2);
            a3 = fmaf(xv.w, wr[kq * 4 + 3], a3);
        }
        float z = (a0 + a1) + (a2 + a3) + bc;
        float u = (row < n) ? gu[(size_t)row * 32 + col] : 0.5f;
        z += -__logf(-__logf(u + 1e-20f) + 1e-20f);
        float m = z;
        #pragma unroll
        for (int off = 16; off > 0; off >>= 1) m = fmaxf(m, __shfl_xor(m, off, 32));
        float ex = __expf(z - m);
        float sum = ex;
        #pragma unroll
        for (int off = 16; off > 0; off >>= 1) sum += __shfl_xor(sum, off, 32);
        if (row < n) out[(size_t)row * 32 + col] = ex / sum;
    }
}

extern "C" void kernel_launch(void* const* d_in, const int* in_sizes, int n_in,
                              void* d_out, int out_size, void* d_ws, size_t ws_size,
                              hipStream_t stream) {
    const float* x        = (const float*)d_in[0];
    const int*   ei       = (const int*)  d_in[1];
    const float* W0       = (const float*)d_in[2];
    const float* att_src0 = (const float*)d_in[3];
    const float* att_dst0 = (const float*)d_in[4];
    const float* bias0    = (const float*)d_in[5];
    const float* fcw0     = (const float*)d_in[6];
    const float* fcb0     = (const float*)d_in[7];
    const float* W1       = (const float*)d_in[8];
    const float* att_src1 = (const float*)d_in[9];
    const float* att_dst1 = (const float*)d_in[10];
    const float* bias1    = (const float*)d_in[11];
    const float* fcw1     = (const float*)d_in[12];
    const float* fcb1     = (const float*)d_in[13];
    const float* out_w    = (const float*)d_in[14];
    const float* out_b    = (const float*)d_in[15];
    const float* gu       = (const float*)d_in[16];

    const int N_ = in_sizes[0] / INDIM;
    const int E_ = in_sizes[1] / 2;

    float* ws = (float*)d_ws;
    size_t off = 0;
    __half* xl = (__half*)(ws + off); off += (size_t)N_ * 64;   // N*128 halves
    float* gat   = ws + off; off += (size_t)N_ * FDIM;
    float* a_src = ws + off; off += (size_t)N_ * HEADS;
    float* a_dst = ws + off; off += (size_t)N_ * HEADS;
    float* Wf    = ws + off; off += 128 * 128;
    float* bf    = ws + off; off += 128;
    float* Wfo   = ws + off; off += 128 * 32;
    float* bfo   = ws + off; off += 32;
    int* deg     = (int*)(ws + off); off += N_;
    int* offs    = (int*)(ws + off); off += N_;
    int* pos     = (int*)(ws + off); off += N_;
    int* bsum    = (int*)(ws + off); off += 1024;
    int* csr_src = (int*)(ws + off); off += E_;

    const int B = 256;
    dim3 blk(B);
    int nb     = (N_ + SCAN_B - 1) / SCAN_B;
    int g_n    = (N_ + B - 1) / B;
    int g_e    = (E_ + B - 1) / B;
    int g64    = (N_ + 63) / 64;
    int g_gath = (N_ + 3) / 4;

    // ---- CSR build (shared by both layers) + weight fusion ----
    k_zero   <<<g_n, blk, 0, stream>>>(deg, N_);
    k_count  <<<g_e, blk, 0, stream>>>(ei, E_, deg);
    k_scan1  <<<nb, dim3(SCAN_B), 0, stream>>>(deg, offs, bsum, N_);
    k_scan2  <<<1, dim3(1024), 0, stream>>>(bsum, nb);
    k_scan3  <<<g_n, blk, 0, stream>>>(offs, bsum, pos, N_);
    k_fill   <<<g_e, blk, 0, stream>>>(ei, E_, pos, csr_src);
    k_fuse_w <<<258, dim3(128), 0, stream>>>(fcw0, fcb0, W1, fcw1, fcb1, out_w, out_b,
                                             Wf, bf, Wfo, bfo);

    // ---- layer 1 ----
    k_gemm_att1 <<<g64,    blk, 0, stream>>>(x, W0, att_src0, att_dst0, xl, a_src, a_dst, N_);
    k_gather    <<<g_gath, blk, 0, stream>>>(offs, csr_src, E_, xl, a_src, a_dst, bias0, gat, N_);

    // ---- layer 2 (fc fused into GEMM via Wf) ----
    k_gemm_att2 <<<g64,    blk, 0, stream>>>(gat, Wf, bf, att_src1, att_dst1, xl, a_src, a_dst, N_);
    k_gather    <<<g_gath, blk, 0, stream>>>(offs, csr_src, E_, xl, a_src, a_dst, bias1, gat, N_);

    // ---- head (fc fused into final via Wfo) ----
    k_final     <<<g64,    blk, 0, stream>>>(gat, Wfo, bfo, gu, (float*)d_out, N_);
}

// Round 4
// 337.650 us; speedup vs baseline: 4.2745x; 1.3664x over previous
//
#include <hip/hip_runtime.h>
#include <hip/hip_fp16.h>
#include <math.h>

#define HEADS 2
#define FDIM 128
#define INDIM 64
#define ODIM 32
#define NEG_SLOPE 0.2f
#define SCAN_B 256

typedef _Float16 f16x8 __attribute__((ext_vector_type(8)));
typedef float f32x4 __attribute__((ext_vector_type(4)));
union H8 { uint4 u; f16x8 v; __half2 h2[4]; };
union H4 { uint2 u; __half2 h2[2]; };

__device__ __forceinline__ float elu1(float v) { return v > 0.f ? v : __expf(v) - 1.f; }

#define MFMA16(a, b, c) __builtin_amdgcn_mfma_f32_16x16x32_f16((a), (b), (c), 0, 0, 0)

// ---------------- CSR build ----------------
__global__ void k_zero(int* __restrict__ p, int n) {
    int i = blockIdx.x * blockDim.x + threadIdx.x;
    if (i < n) p[i] = 0;
}

__global__ void k_count(const int* __restrict__ ei, int E_, int* __restrict__ deg) {
    int e = blockIdx.x * blockDim.x + threadIdx.x;
    if (e < E_) atomicAdd(&deg[ei[E_ + e]], 1);
}

__global__ void k_scan1(const int* __restrict__ deg, int* __restrict__ offs,
                        int* __restrict__ bsum, int n) {
    __shared__ int sh[SCAN_B];
    int t = threadIdx.x;
    int i = blockIdx.x * SCAN_B + t;
    int v = (i < n) ? deg[i] : 0;
    sh[t] = v;
    __syncthreads();
    for (int off = 1; off < SCAN_B; off <<= 1) {
        int add = (t >= off) ? sh[t - off] : 0;
        __syncthreads();
        sh[t] += add;
        __syncthreads();
    }
    if (i < n) offs[i] = sh[t] - v;
    if (t == SCAN_B - 1) bsum[blockIdx.x] = sh[t];
}

__global__ void k_scan2(int* __restrict__ bsum, int nb) {
    __shared__ int sh[1024];
    int t = threadIdx.x;
    int v = (t < nb) ? bsum[t] : 0;
    sh[t] = v;
    __syncthreads();
    for (int off = 1; off < 1024; off <<= 1) {
        int add = (t >= off) ? sh[t - off] : 0;
        __syncthreads();
        sh[t] += add;
        __syncthreads();
    }
    if (t < nb) bsum[t] = sh[t] - v;
}

__global__ void k_scan3(int* __restrict__ offs, const int* __restrict__ bsum,
                        int* __restrict__ pos, int n) {
    int i = blockIdx.x * blockDim.x + threadIdx.x;
    if (i < n) {
        int v = offs[i] + bsum[i >> 8];
        offs[i] = v;
        pos[i] = v;
    }
}

__global__ void k_fill(const int* __restrict__ ei, int E_, int* __restrict__ pos,
                       int* __restrict__ csr_src) {
    int e = blockIdx.x * blockDim.x + threadIdx.x;
    if (e < E_) {
        int d = ei[E_ + e];
        int slot = atomicAdd(&pos[d], 1);
        csr_src[slot] = ei[e];
    }
}

// ---------- weight precompute ----------
// W0T[c][k]  = W0[k][c]            fp16  (128 x 64)
// WfT[c][k]  = (fcw0@W1)[k][c]     fp16  (128 x 128)
// bf[c]      = fcb0@W1             fp32
// WfoT[c][k] = (fcw1@out_w)[k][c]  fp16  (32 x 128)
// bfo[c]     = fcb1@out_w + out_b  fp32
__global__ __launch_bounds__(128) void k_fuse_w(
    const float* __restrict__ W0,
    const float* __restrict__ fcw0, const float* __restrict__ fcb0, const float* __restrict__ W1,
    const float* __restrict__ fcw1, const float* __restrict__ fcb1,
    const float* __restrict__ out_w, const float* __restrict__ out_b,
    __half* __restrict__ W0T, __half* __restrict__ WfT, float* __restrict__ bf,
    __half* __restrict__ WfoT, float* __restrict__ bfo)
{
    int b = blockIdx.x, c = threadIdx.x;
    if (b < 128) {                       // WfT rows
        float acc = 0.f;
        for (int j = 0; j < 64; ++j) acc = fmaf(fcw0[b * 64 + j], W1[j * 128 + c], acc);
        WfT[c * 128 + b] = __float2half(acc);
    } else if (b == 128) {
        float acc = 0.f;
        for (int j = 0; j < 64; ++j) acc = fmaf(fcb0[j], W1[j * 128 + c], acc);
        bf[c] = acc;
    } else if (b < 257) {                // WfoT
        int k = b - 129;
        if (c < 32) {
            float acc = 0.f;
            for (int j = 0; j < 64; ++j) acc = fmaf(fcw1[k * 64 + j], out_w[j * 32 + c], acc);
            WfoT[c * 128 + k] = __float2half(acc);
        }
    } else if (b == 257) {
        if (c < 32) {
            float acc = 0.f;
            for (int j = 0; j < 64; ++j) acc = fmaf(fcb1[j], out_w[j * 32 + c], acc);
            bfo[c] = acc + out_b[c];
        }
    } else {                             // W0T
        int k = b - 258;                 // 0..63
        W0T[c * 64 + k] = __float2half(W0[k * 128 + c]);
    }
}

// ---------- layer-1: xl = x@W0 (fp16 out) + a_src/a_dst, MFMA ----------
// D = W0T-tile (16ch x 32k) . x^T-tile (32k x 16rows):
// lane: m=lane&15 -> x-row, q=lane>>4; acc[nt][reg] = channel nt*16+q*4+reg
__global__ __launch_bounds__(256, 2) void k_mm_att1(
    const float* __restrict__ x, const __half* __restrict__ w0t,
    const float* __restrict__ att_src, const float* __restrict__ att_dst,
    __half* __restrict__ xl, float* __restrict__ a_src, float* __restrict__ a_dst,
    int n, int ntiles, int nwaves)
{
    int lane = threadIdx.x & 63;
    int wid = blockIdx.x * 4 + (threadIdx.x >> 6);
    int m = lane & 15, q = lane >> 4;

    H8 A[8][2];
    #pragma unroll
    for (int nt = 0; nt < 8; ++nt)
        #pragma unroll
        for (int kt = 0; kt < 2; ++kt)
            A[nt][kt].u = *(const uint4*)(w0t + (size_t)(nt * 16 + m) * 64 + kt * 32 + q * 8);

    for (int t = wid; t < ntiles; t += nwaves) {
        int rb = t * 16;
        int row = rb + m; if (row >= n) row = n - 1;
        H8 B[2];
        #pragma unroll
        for (int kt = 0; kt < 2; ++kt) {
            const float4* p = (const float4*)(x + (size_t)row * 64 + kt * 32 + q * 8);
            float4 p0 = p[0], p1 = p[1];
            B[kt].h2[0] = __floats2half2_rn(p0.x, p0.y);
            B[kt].h2[1] = __floats2half2_rn(p0.z, p0.w);
            B[kt].h2[2] = __floats2half2_rn(p1.x, p1.y);
            B[kt].h2[3] = __floats2half2_rn(p1.z, p1.w);
        }
        f32x4 acc[8];
        #pragma unroll
        for (int nt = 0; nt < 8; ++nt) {
            acc[nt] = {0.f, 0.f, 0.f, 0.f};
            acc[nt] = MFMA16(A[nt][0].v, B[0].v, acc[nt]);
            acc[nt] = MFMA16(A[nt][1].v, B[1].v, acc[nt]);
        }
        float ps0 = 0.f, ps1 = 0.f, pd0 = 0.f, pd1 = 0.f;
        bool ok = (rb + m) < n;
        #pragma unroll
        for (int nt = 0; nt < 8; ++nt) {
            float4 asv = *(const float4*)(att_src + nt * 16 + q * 4);
            float4 adv = *(const float4*)(att_dst + nt * 16 + q * 4);
            f32x4 d = acc[nt];
            H4 pk;
            pk.h2[0] = __floats2half2_rn(d[0], d[1]);
            pk.h2[1] = __floats2half2_rn(d[2], d[3]);
            if (ok) *(uint2*)(xl + (size_t)(rb + m) * 128 + nt * 16 + q * 4) = pk.u;
            float cs = d[0] * asv.x + d[1] * asv.y + d[2] * asv.z + d[3] * asv.w;
            float cd = d[0] * adv.x + d[1] * adv.y + d[2] * adv.z + d[3] * adv.w;
            if (nt < 4) { ps0 += cs; pd0 += cd; } else { ps1 += cs; pd1 += cd; }
        }
        ps0 += __shfl_xor(ps0, 16, 64); ps0 += __shfl_xor(ps0, 32, 64);
        ps1 += __shfl_xor(ps1, 16, 64); ps1 += __shfl_xor(ps1, 32, 64);
        pd0 += __shfl_xor(pd0, 16, 64); pd0 += __shfl_xor(pd0, 32, 64);
        pd1 += __shfl_xor(pd1, 16, 64); pd1 += __shfl_xor(pd1, 32, 64);
        if (lane < 16 && ok) {
            *(float2*)(a_src + (size_t)(rb + m) * 2) = make_float2(ps0, ps1);
            *(float2*)(a_dst + (size_t)(rb + m) * 2) = make_float2(pd0, pd1);
        }
    }
}

// ---------- layer-2: xl = elu(gat)@Wf + bf (fp16 out) + a_src/a_dst ----------
__global__ __launch_bounds__(256, 2) void k_mm_att2(
    const float* __restrict__ g, const __half* __restrict__ wft, const float* __restrict__ bf,
    const float* __restrict__ att_src, const float* __restrict__ att_dst,
    __half* __restrict__ xl, float* __restrict__ a_src, float* __restrict__ a_dst,
    int n, int ntiles, int nwaves)
{
    int lane = threadIdx.x & 63;
    int wid = blockIdx.x * 4 + (threadIdx.x >> 6);
    int m = lane & 15, q = lane >> 4;

    H8 A[8][4];
    #pragma unroll
    for (int nt = 0; nt < 8; ++nt)
        #pragma unroll
        for (int kt = 0; kt < 4; ++kt)
            A[nt][kt].u = *(const uint4*)(wft + (size_t)(nt * 16 + m) * 128 + kt * 32 + q * 8);

    for (int t = wid; t < ntiles; t += nwaves) {
        int rb = t * 16;
        int row = rb + m; if (row >= n) row = n - 1;
        H8 B[4];
        #pragma unroll
        for (int kt = 0; kt < 4; ++kt) {
            const float4* p = (const float4*)(g + (size_t)row * 128 + kt * 32 + q * 8);
            float4 p0 = p[0], p1 = p[1];
            B[kt].h2[0] = __floats2half2_rn(elu1(p0.x), elu1(p0.y));
            B[kt].h2[1] = __floats2half2_rn(elu1(p0.z), elu1(p0.w));
            B[kt].h2[2] = __floats2half2_rn(elu1(p1.x), elu1(p1.y));
            B[kt].h2[3] = __floats2half2_rn(elu1(p1.z), elu1(p1.w));
        }
        f32x4 acc[8];
        #pragma unroll
        for (int nt = 0; nt < 8; ++nt) {
            acc[nt] = {0.f, 0.f, 0.f, 0.f};
            #pragma unroll
            for (int kt = 0; kt < 4; ++kt)
                acc[nt] = MFMA16(A[nt][kt].v, B[kt].v, acc[nt]);
        }
        float ps0 = 0.f, ps1 = 0.f, pd0 = 0.f, pd1 = 0.f;
        bool ok = (rb + m) < n;
        #pragma unroll
        for (int nt = 0; nt < 8; ++nt) {
            float4 bfv = *(const float4*)(bf + nt * 16 + q * 4);
            float4 asv = *(const float4*)(att_src + nt * 16 + q * 4);
            float4 adv = *(const float4*)(att_dst + nt * 16 + q * 4);
            f32x4 d = acc[nt];
            d[0] += bfv.x; d[1] += bfv.y; d[2] += bfv.z; d[3] += bfv.w;
            H4 pk;
            pk.h2[0] = __floats2half2_rn(d[0], d[1]);
            pk.h2[1] = __floats2half2_rn(d[2], d[3]);
            if (ok) *(uint2*)(xl + (size_t)(rb + m) * 128 + nt * 16 + q * 4) = pk.u;
            float cs = d[0] * asv.x + d[1] * asv.y + d[2] * asv.z + d[3] * asv.w;
            float cd = d[0] * adv.x + d[1] * adv.y + d[2] * adv.z + d[3] * adv.w;
            if (nt < 4) { ps0 += cs; pd0 += cd; } else { ps1 += cs; pd1 += cd; }
        }
        ps0 += __shfl_xor(ps0, 16, 64); ps0 += __shfl_xor(ps0, 32, 64);
        ps1 += __shfl_xor(ps1, 16, 64); ps1 += __shfl_xor(ps1, 32, 64);
        pd0 += __shfl_xor(pd0, 16, 64); pd0 += __shfl_xor(pd0, 32, 64);
        pd1 += __shfl_xor(pd1, 16, 64); pd1 += __shfl_xor(pd1, 32, 64);
        if (lane < 16 && ok) {
            *(float2*)(a_src + (size_t)(rb + m) * 2) = make_float2(ps0, ps1);
            *(float2*)(a_dst + (size_t)(rb + m) * 2) = make_float2(pd0, pd1);
        }
    }
}

// ---------- gather v3 (unchanged): 1 wave/dst, 4 edges/iter, fp16 xl ----------
__global__ __launch_bounds__(256, 4) void k_gather(
    const int* __restrict__ offs, const int* __restrict__ csr_src, int E_,
    const __half* __restrict__ xl, const float* __restrict__ a_src,
    const float* __restrict__ a_dst, const float* __restrict__ bias,
    float* __restrict__ out, int n)
{
    int t = threadIdx.x;
    int lane = t & 63;
    int d = blockIdx.x * 4 + (t >> 6);
    if (d >= n) return;
    int eh = lane >> 4;
    int cq = lane & 15;
    int h = cq >> 3;
    float ad = a_dst[d * 2 + h];
    const float4* bp = (const float4*)(bias + cq * 8);
    float4 b0 = bp[0], b1 = bp[1];
    int start = offs[d];
    int end = (d + 1 < n) ? offs[d + 1] : E_;
    float acc[8] = {0.f, 0.f, 0.f, 0.f, 0.f, 0.f, 0.f, 0.f};
    float den = 0.f;
    for (int j0 = start; j0 < end; j0 += 4) {
        int j = j0 + eh;
        bool valid = j < end;
        int s = valid ? csr_src[j] : d;
        float a = a_src[s * 2 + h] + ad;
        a = (a >= 0.f) ? a : NEG_SLOPE * a;
        float w = valid ? __expf(a) : 0.f;
        float4 raw = *(const float4*)(xl + (size_t)s * 128 + cq * 8);
        __half2* hp = (__half2*)&raw;
        float2 f0 = __half22float2(hp[0]);
        float2 f1 = __half22float2(hp[1]);
        float2 f2 = __half22float2(hp[2]);
        float2 f3 = __half22float2(hp[3]);
        acc[0] = fmaf(w, f0.x, acc[0]); acc[1] = fmaf(w, f0.y, acc[1]);
        acc[2] = fmaf(w, f1.x, acc[2]); acc[3] = fmaf(w, f1.y, acc[3]);
        acc[4] = fmaf(w, f2.x, acc[4]); acc[5] = fmaf(w, f2.y, acc[5]);
        acc[6] = fmaf(w, f3.x, acc[6]); acc[7] = fmaf(w, f3.y, acc[7]);
        den += w;
    }
    if (eh == 0) {
        float a = a_src[d * 2 + h] + ad;
        a = (a >= 0.f) ? a : NEG_SLOPE * a;
        float w = __expf(a);
        float4 raw = *(const float4*)(xl + (size_t)d * 128 + cq * 8);
        __half2* hp = (__half2*)&raw;
        float2 f0 = __half22float2(hp[0]);
        float2 f1 = __half22float2(hp[1]);
        float2 f2 = __half22float2(hp[2]);
        float2 f3 = __half22float2(hp[3]);
        acc[0] = fmaf(w, f0.x, acc[0]); acc[1] = fmaf(w, f0.y, acc[1]);
        acc[2] = fmaf(w, f1.x, acc[2]); acc[3] = fmaf(w, f1.y, acc[3]);
        acc[4] = fmaf(w, f2.x, acc[4]); acc[5] = fmaf(w, f2.y, acc[5]);
        acc[6] = fmaf(w, f3.x, acc[6]); acc[7] = fmaf(w, f3.y, acc[7]);
        den += w;
    }
    #pragma unroll
    for (int i = 0; i < 8; ++i) {
        acc[i] += __shfl_xor(acc[i], 16, 64);
        acc[i] += __shfl_xor(acc[i], 32, 64);
    }
    den += __shfl_xor(den, 16, 64);
    den += __shfl_xor(den, 32, 64);
    if (eh == 0) {
        float inv = 1.f / (den + 1e-16f);
        float4 o0 = make_float4(fmaf(acc[0], inv, b0.x), fmaf(acc[1], inv, b0.y),
                                fmaf(acc[2], inv, b0.z), fmaf(acc[3], inv, b0.w));
        float4 o1 = make_float4(fmaf(acc[4], inv, b1.x), fmaf(acc[5], inv, b1.y),
                                fmaf(acc[6], inv, b1.z), fmaf(acc[7], inv, b1.w));
        float4* op = (float4*)(out + (size_t)d * 128 + cq * 8);
        op[0] = o0; op[1] = o1;
    }
}

// ---------- head: softmax(elu(gat2)@Wfo + bfo + gumbel), MFMA ----------
__global__ __launch_bounds__(256, 2) void k_mm_final(
    const float* __restrict__ g, const __half* __restrict__ wfot, const float* __restrict__ bfo,
    const float* __restrict__ gu, float* __restrict__ out, int n, int ntiles, int nwaves)
{
    int lane = threadIdx.x & 63;
    int wid = blockIdx.x * 4 + (threadIdx.x >> 6);
    int m = lane & 15, q = lane >> 4;

    H8 A[2][4];
    #pragma unroll
    for (int nt = 0; nt < 2; ++nt)
        #pragma unroll
        for (int kt = 0; kt < 4; ++kt)
            A[nt][kt].u = *(const uint4*)(wfot + (size_t)(nt * 16 + m) * 128 + kt * 32 + q * 8);

    for (int t = wid; t < ntiles; t += nwaves) {
        int rb = t * 16;
        int row = rb + m; if (row >= n) row = n - 1;
        H8 B[4];
        #pragma unroll
        for (int kt = 0; kt < 4; ++kt) {
            const float4* p = (const float4*)(g + (size_t)row * 128 + kt * 32 + q * 8);
            float4 p0 = p[0], p1 = p[1];
            B[kt].h2[0] = __floats2half2_rn(elu1(p0.x), elu1(p0.y));
            B[kt].h2[1] = __floats2half2_rn(elu1(p0.z), elu1(p0.w));
            B[kt].h2[2] = __floats2half2_rn(elu1(p1.x), elu1(p1.y));
            B[kt].h2[3] = __floats2half2_rn(elu1(p1.z), elu1(p1.w));
        }
        f32x4 acc[2];
        #pragma unroll
        for (int nt = 0; nt < 2; ++nt) {
            acc[nt] = {0.f, 0.f, 0.f, 0.f};
            #pragma unroll
            for (int kt = 0; kt < 4; ++kt)
                acc[nt] = MFMA16(A[nt][kt].v, B[kt].v, acc[nt]);
        }
        float z[8];
        #pragma unroll
        for (int nt = 0; nt < 2; ++nt) {
            float4 bv = *(const float4*)(bfo + nt * 16 + q * 4);
            float4 uv = *(const float4*)(gu + (size_t)row * 32 + nt * 16 + q * 4);
            z[nt * 4 + 0] = acc[nt][0] + bv.x - __logf(-__logf(uv.x + 1e-20f) + 1e-20f);
            z[nt * 4 + 1] = acc[nt][1] + bv.y - __logf(-__logf(uv.y + 1e-20f) + 1e-20f);
            z[nt * 4 + 2] = acc[nt][2] + bv.z - __logf(-__logf(uv.z + 1e-20f) + 1e-20f);
            z[nt * 4 + 3] = acc[nt][3] + bv.w - __logf(-__logf(uv.w + 1e-20f) + 1e-20f);
        }
        float mx = z[0];
        #pragma unroll
        for (int i = 1; i < 8; ++i) mx = fmaxf(mx, z[i]);
        mx = fmaxf(mx, __shfl_xor(mx, 16, 64));
        mx = fmaxf(mx, __shfl_xor(mx, 32, 64));
        float sum = 0.f;
        #pragma unroll
        for (int i = 0; i < 8; ++i) { z[i] = __expf(z[i] - mx); sum += z[i]; }
        sum += __shfl_xor(sum, 16, 64);
        sum += __shfl_xor(sum, 32, 64);
        float inv = 1.f / sum;
        if (rb + m < n) {
            #pragma unroll
            for (int nt = 0; nt < 2; ++nt) {
                float4 o = make_float4(z[nt * 4 + 0] * inv, z[nt * 4 + 1] * inv,
                                       z[nt * 4 + 2] * inv, z[nt * 4 + 3] * inv);
                *(float4*)(out + (size_t)(rb + m) * 32 + nt * 16 + q * 4) = o;
            }
        }
    }
}

extern "C" void kernel_launch(void* const* d_in, const int* in_sizes, int n_in,
                              void* d_out, int out_size, void* d_ws, size_t ws_size,
                              hipStream_t stream) {
    const float* x        = (const float*)d_in[0];
    const int*   ei       = (const int*)  d_in[1];
    const float* W0       = (const float*)d_in[2];
    const float* att_src0 = (const float*)d_in[3];
    const float* att_dst0 = (const float*)d_in[4];
    const float* bias0    = (const float*)d_in[5];
    const float* fcw0     = (const float*)d_in[6];
    const float* fcb0     = (const float*)d_in[7];
    const float* W1       = (const float*)d_in[8];
    const float* att_src1 = (const float*)d_in[9];
    const float* att_dst1 = (const float*)d_in[10];
    const float* bias1    = (const float*)d_in[11];
    const float* fcw1     = (const float*)d_in[12];
    const float* fcb1     = (const float*)d_in[13];
    const float* out_w    = (const float*)d_in[14];
    const float* out_b    = (const float*)d_in[15];
    const float* gu       = (const float*)d_in[16];

    const int N_ = in_sizes[0] / INDIM;
    const int E_ = in_sizes[1] / 2;

    float* ws = (float*)d_ws;
    size_t off = 0;
    __half* xl  = (__half*)(ws + off); off += (size_t)N_ * 64;     // N*128 halves
    float* gat   = ws + off; off += (size_t)N_ * FDIM;
    float* a_src = ws + off; off += (size_t)N_ * HEADS;
    float* a_dst = ws + off; off += (size_t)N_ * HEADS;
    __half* W0T  = (__half*)(ws + off); off += 128 * 64 / 2;
    __half* WfT  = (__half*)(ws + off); off += 128 * 128 / 2;
    __half* WfoT = (__half*)(ws + off); off += 32 * 128 / 2;
    float* bf    = ws + off; off += 128;
    float* bfo   = ws + off; off += 32;
    int* deg     = (int*)(ws + off); off += N_;
    int* offs    = (int*)(ws + off); off += N_;
    int* pos     = (int*)(ws + off); off += N_;
    int* bsum    = (int*)(ws + off); off += 1024;
    int* csr_src = (int*)(ws + off); off += E_;

    const int B = 256;
    dim3 blk(B);
    int nb     = (N_ + SCAN_B - 1) / SCAN_B;
    int g_n    = (N_ + B - 1) / B;
    int g_e    = (E_ + B - 1) / B;
    int g_gath = (N_ + 3) / 4;
    int ntiles = (N_ + 15) / 16;
    int GMM    = 384;
    int nwaves = GMM * 4;

    // ---- CSR build + weight fusion/transpose ----
    k_zero   <<<g_n, blk, 0, stream>>>(deg, N_);
    k_count  <<<g_e, blk, 0, stream>>>(ei, E_, deg);
    k_scan1  <<<nb, dim3(SCAN_B), 0, stream>>>(deg, offs, bsum, N_);
    k_scan2  <<<1, dim3(1024), 0, stream>>>(bsum, nb);
    k_scan3  <<<g_n, blk, 0, stream>>>(offs, bsum, pos, N_);
    k_fill   <<<g_e, blk, 0, stream>>>(ei, E_, pos, csr_src);
    k_fuse_w <<<322, dim3(128), 0, stream>>>(W0, fcw0, fcb0, W1, fcw1, fcb1, out_w, out_b,
                                             W0T, WfT, bf, WfoT, bfo);

    // ---- layer 1 ----
    k_mm_att1 <<<GMM,    blk, 0, stream>>>(x, W0T, att_src0, att_dst0, xl, a_src, a_dst,
                                           N_, ntiles, nwaves);
    k_gather  <<<g_gath, blk, 0, stream>>>(offs, csr_src, E_, xl, a_src, a_dst, bias0, gat, N_);

    // ---- layer 2 (fc0 fused via WfT) ----
    k_mm_att2 <<<GMM,    blk, 0, stream>>>(gat, WfT, bf, att_src1, att_dst1, xl, a_src, a_dst,
                                           N_, ntiles, nwaves);
    k_gather  <<<g_gath, blk, 0, stream>>>(offs, csr_src, E_, xl, a_src, a_dst, bias1, gat, N_);

    // ---- head (fc1 + out fused via WfoT) ----
    k_mm_final <<<GMM,   blk, 0, stream>>>(gat, WfoT, bfo, gu, (float*)d_out, N_, ntiles, nwaves);
}